// Round 11
// baseline (273.848 us; speedup 1.0000x reference)
//
#include <hip/hip_runtime.h>
#include <cmath>

#define NB 16
#define TAILV 3.0f
#define MINV 0.001f
#define CSC 0.984f   // 1 - NB*MINV

typedef __attribute__((ext_vector_type(8))) _Float16 half8;
typedef __attribute__((ext_vector_type(4))) float f32x4;

#define MFMA16(a,b,c) __builtin_amdgcn_mfma_f32_16x16x32_f16(a,b,c,0,0,0)

__device__ __forceinline__ ushort f2h(float f) {
    union { _Float16 h; ushort u; } v; v.h = (_Float16)f; return v.u;
}
__device__ __forceinline__ float softplus_f(float x) {
    return (x > 20.0f) ? x : __logf(1.0f + __expf(x));
}

// ---- prologue: convert/transpose weights into d_ws (fp16, [N][K]) ----
// W3T: [1568][256] un-padded (n = original output col).  W2T: [256][256].  W1T: [256][32].
__global__ void __launch_bounds__(256)
cvt_weights(const float* __restrict__ W1, const float* __restrict__ W2,
            const float* __restrict__ W3,
            ushort* __restrict__ W3T, ushort* __restrict__ W2T,
            ushort* __restrict__ W1T)
{
    const int b = blockIdx.x, t = threadIdx.x;
    if (b < 1568) {
        int idx = b * 256 + t;
        int n = idx >> 8, k = idx & 255;
        W3T[idx] = f2h(W3[(size_t)k * 1568 + n]);
    } else if (b < 1568 + 256) {
        int idx = (b - 1568) * 256 + t;
        int n = idx >> 8, k = idx & 255;
        W2T[idx] = f2h(W2[(size_t)k * 256 + n]);
    } else {   // 32 blocks for W1 (8192 elems)
        int idx = (b - 1824) * 256 + t;
        int n = idx >> 5, k = idx & 31;
        W1T[idx] = f2h(W1[(size_t)k * 256 + n]);
    }
}

// ---- fused main kernel: 64 batch rows / block, 4 waves, 1024 blocks ----
// Phase 4 un-padded: wave w streams 25 16-col tiles covering its 8 dims
// (1568 = 98 exact tiles; waves 1,3 start mid-dim, boundary lanes held in
// accumulators across the spline and flushed after). Barrier-free phase 4.
extern "C" __global__ void __launch_bounds__(256, 2)
rq_mfma(const float* __restrict__ x1, const float* __restrict__ x2,
        const float* __restrict__ b1, const float* __restrict__ b2,
        const float* __restrict__ b3,
        const ushort* __restrict__ W1T, const ushort* __restrict__ W2T,
        const ushort* __restrict__ W3T,
        float* __restrict__ zout, float* __restrict__ ldout)
{
    __shared__ char smem[60416];
    float*  sX2  = (float*)smem;                    // [64][33] f32 = 8448
    float*  sLDw = (float*)(smem + 8448);           // [64][5] f32 = 1280
    char*   U    = smem + 9728;                     // 50688-byte union
    ushort* R0   = (ushort*)U;                      // [32][264] fp16 = 16896
    ushort* R1   = (ushort*)(U + 16896);            // [32][264]
    ushort* R2   = (ushort*)(U + 33792);            // [32][264]
    ushort* sA1  = R2;                              // [64][40] fp16 = 5120
    float*  sPw  = (float*)U;                       // 4 x [64][49] f32 = 50176

    const int tid  = threadIdx.x;
    const int row0 = blockIdx.x * 64;
    const int wave = tid >> 6, lane = tid & 63;
    const int ln = lane & 15, kg = lane >> 4;       // frag: m/n=ln, k-group=kg

    // ---- phase 0: stage x1 (->fp16, R2) and x2 (f32) ----
    {
        int r = tid >> 2, c = (tid & 3) << 3;
        float4 v0 = *(const float4*)(x1 + (size_t)(row0 + r) * 32 + c);
        float4 v1 = *(const float4*)(x1 + (size_t)(row0 + r) * 32 + c + 4);
        sA1[r*40 + c    ] = f2h(v0.x); sA1[r*40 + c + 1] = f2h(v0.y);
        sA1[r*40 + c + 2] = f2h(v0.z); sA1[r*40 + c + 3] = f2h(v0.w);
        sA1[r*40 + c + 4] = f2h(v1.x); sA1[r*40 + c + 5] = f2h(v1.y);
        sA1[r*40 + c + 6] = f2h(v1.z); sA1[r*40 + c + 7] = f2h(v1.w);
        float4 w0 = *(const float4*)(x2 + (size_t)(row0 + r) * 32 + c);
        float4 w1 = *(const float4*)(x2 + (size_t)(row0 + r) * 32 + c + 4);
        sX2[r*33 + c    ] = w0.x; sX2[r*33 + c + 1] = w0.y;
        sX2[r*33 + c + 2] = w0.z; sX2[r*33 + c + 3] = w0.w;
        sX2[r*33 + c + 4] = w1.x; sX2[r*33 + c + 5] = w1.y;
        sX2[r*33 + c + 6] = w1.z; sX2[r*33 + c + 7] = w1.w;
    }
    __syncthreads();

    // ---- phase 1: h1 = relu(x1 @ W1 + b1); 4 M-tiles, K=32 ----
    {
        half8 a[4];
        #pragma unroll
        for (int m = 0; m < 4; ++m)
            a[m] = *(const half8*)(sA1 + (m*16 + ln)*40 + kg*8);
        #pragma unroll
        for (int nt = 0; nt < 4; ++nt) {
            int n = wave*64 + nt*16 + ln;
            half8 bfr = *(const half8*)(W1T + n*32 + kg*8);
            float bias = b1[n];
            f32x4 zr = {0.f,0.f,0.f,0.f};
            #pragma unroll
            for (int m = 0; m < 4; ++m) {
                f32x4 cm = MFMA16(a[m], bfr, zr);
                ushort* dst = (m < 2) ? R0 : R1;
                int rb = (m & 1) * 16;
                #pragma unroll
                for (int g = 0; g < 4; ++g)
                    dst[(rb + kg*4 + g)*264 + n] = f2h(fmaxf(cm[g] + bias, 0.f));
            }
        }
    }
    __syncthreads();

    // ---- phase 2: h2 = relu(h1 @ W2 + b2), two 32-row half-passes ----
    #pragma unroll
    for (int part = 0; part < 2; ++part) {
        const ushort* S = (part == 0) ? R0 : R1;   // h1 rows
        ushort*       D = (part == 0) ? R2 : R0;   // h2 rows
        half8 a0[8], a1[8];
        #pragma unroll
        for (int ks = 0; ks < 8; ++ks) {
            a0[ks] = *(const half8*)(S + ln*264 + ks*32 + kg*8);
            a1[ks] = *(const half8*)(S + (16 + ln)*264 + ks*32 + kg*8);
        }
        #pragma unroll
        for (int nt = 0; nt < 4; ++nt) {
            int n = wave*64 + nt*16 + ln;
            f32x4 c0 = {0,0,0,0}, c1 = {0,0,0,0};
            const ushort* bp = W2T + (size_t)n*256 + kg*8;
            #pragma unroll
            for (int ks = 0; ks < 8; ++ks) {
                half8 bfr = *(const half8*)(bp + ks*32);
                c0 = MFMA16(a0[ks], bfr, c0);
                c1 = MFMA16(a1[ks], bfr, c1);
            }
            float bias = b2[n];
            #pragma unroll
            for (int g = 0; g < 4; ++g) {
                D[(kg*4 + g)*264 + n]      = f2h(fmaxf(c0[g] + bias, 0.f));
                D[(16 + kg*4 + g)*264 + n] = f2h(fmaxf(c1[g] + bias, 0.f));
            }
        }
        __syncthreads();
    }

    // ---- phase 3: hoist GEMM3 A-fragments (4 M-tiles x 8 ks = 128 regs) ----
    half8 A[4][8];
    #pragma unroll
    for (int m = 0; m < 4; ++m) {
        const ushort* src = (m < 2) ? R2 : R0;     // h2 rows 0-31 / 32-63
        int rb = (m & 1) * 16;
        #pragma unroll
        for (int ks = 0; ks < 8; ++ks)
            A[m][ks] = *(const half8*)(src + (rb + ln)*264 + ks*32 + kg*8);
    }
    __syncthreads();   // staging dead; sPw overlays U

    // ---- phase 4: un-padded GEMM3 + rolling fused spline ----
    float* myP = sPw + wave * (64 * 49);
    float  ldacc = 0.f;
    const int ts = (49 * wave) >> 1;               // first tile: {0,24,49,73}
    int cd = wave * 8;                             // current dim

    auto do_spline = [&](int dim) {
        const float* pp = myP + lane * 49;
        const float x  = sX2[lane*33 + dim];
        const float xc = fminf(fmaxf(x, -TAILV), TAILV);

        float e[NB]; float mx = -1e30f;
        #pragma unroll
        for (int k = 0; k < NB; ++k) { e[k] = pp[k]; mx = fmaxf(mx, e[k]); }
        float s = 0.f;
        #pragma unroll
        for (int k = 0; k < NB; ++k) { e[k] = __expf(e[k] - mx); s += e[k]; }
        const float inv = 1.f / s;

        int idx = 0; float xk = -TAILV, xk1 = TAILV, cum = 0.f;
        #pragma unroll
        for (int k = 0; k < NB; ++k) {
            float lo = -TAILV + 2.f * TAILV * cum;
            cum += MINV + CSC * e[k] * inv;
            float hi = -TAILV + 2.f * TAILV * cum;
            if (lo <= xc) { idx = k; xk = lo; xk1 = hi; }
        }

        float eh[NB]; float mh = -1e30f;
        #pragma unroll
        for (int k = 0; k < NB; ++k) { eh[k] = pp[NB + k]; mh = fmaxf(mh, eh[k]); }
        float sh = 0.f;
        #pragma unroll
        for (int k = 0; k < NB; ++k) { eh[k] = __expf(eh[k] - mh); sh += eh[k]; }
        const float invh = 1.f / sh;

        float yk = -TAILV, yk1 = TAILV; cum = 0.f;
        #pragma unroll
        for (int k = 0; k < NB; ++k) {
            float lo = -TAILV + 2.f * TAILV * cum;
            cum += MINV + CSC * eh[k] * invh;
            float hi = -TAILV + 2.f * TAILV * cum;
            if (k == idx) { yk = lo; yk1 = hi; }
        }

        const float d0 = MINV + softplus_f(pp[2*NB + idx]);
        const float d1 = MINV + softplus_f(pp[2*NB + idx + 1]);

        const float wd = xk1 - xk, hd = yk1 - yk;
        const float sk = hd / wd;
        const float xi = (xc - xk) / wd;
        const float xim = xi * (1.f - xi);
        const float alpha = hd * (sk * xi * xi + d0 * xim);
        const float beta  = sk + (d1 + d0 - 2.f * sk) * xim;
        const float z     = yk + alpha / beta;
        const float om    = 1.f - xi;
        const float dn    = sk * sk * (d1 * xi * xi + 2.f * sk * xim + d0 * om * om);
        const float ld    = __logf(dn) - 2.f * __logf(beta);

        const bool inside = (x >= -TAILV) && (x <= TAILV);
        zout[(size_t)(row0 + lane) * 32 + dim] = inside ? z : x;
        ldacc += inside ? ld : 0.f;
    };

    half8 bcur[8], bnxt[8];
    {
        const ushort* bp = W3T + (size_t)(ts*16 + ln)*256 + kg*8;
        #pragma unroll
        for (int ks = 0; ks < 8; ++ks) bcur[ks] = *(const half8*)(bp + ks*32);
    }

    for (int t = ts; t < ts + 25; ++t) {
        if (t < ts + 24) {   // prefetch next tile
            const ushort* bp = W3T + (size_t)((t+1)*16 + ln)*256 + kg*8;
            #pragma unroll
            for (int ks = 0; ks < 8; ++ks) bnxt[ks] = *(const half8*)(bp + ks*32);
        }
        const float bias = b3[(t << 4) + ln];
        f32x4 c[4];
        #pragma unroll
        for (int m = 0; m < 4; ++m) c[m] = (f32x4){0,0,0,0};
        #pragma unroll
        for (int ks = 0; ks < 8; ++ks)
            #pragma unroll
            for (int m = 0; m < 4; ++m)
                c[m] = MFMA16(A[m][ks], bcur[ks], c[m]);

        const int p = (t << 4) + ln - 49 * cd;     // col within current dim
        if (p >= 0 && p < 49) {
            #pragma unroll
            for (int m = 0; m < 4; ++m)
                #pragma unroll
                for (int g = 0; g < 4; ++g)
                    myP[(m*16 + kg*4 + g)*49 + p] = c[m][g] + bias;
        }
        if (49 * cd + 48 < ((t + 1) << 4)) {       // tile completes current dim
            do_spline(cd);
            cd += 1;
            const int p2 = p - 49;                 // leftover lanes -> new dim head
            if (p2 >= 0) {
                #pragma unroll
                for (int m = 0; m < 4; ++m)
                    #pragma unroll
                    for (int g = 0; g < 4; ++g)
                        myP[(m*16 + kg*4 + g)*49 + p2] = c[m][g] + bias;
            }
        }
        if (t < ts + 24) {
            #pragma unroll
            for (int ks = 0; ks < 8; ++ks) bcur[ks] = bnxt[ks];
        }
    }

    sLDw[lane*5 + wave] = ldacc;
    __syncthreads();

    // ---- phase 5: log_det reduction across waves ----
    if (tid < 64) {
        float sld = sLDw[tid*5 + 0] + sLDw[tid*5 + 1]
                  + sLDw[tid*5 + 2] + sLDw[tid*5 + 3];
        ldout[row0 + tid] = sld;
    }
}

extern "C" void kernel_launch(void* const* d_in, const int* in_sizes, int n_in,
                              void* d_out, int out_size, void* d_ws, size_t ws_size,
                              hipStream_t stream)
{
    const float* x1 = (const float*)d_in[0];
    const float* x2 = (const float*)d_in[1];
    const float* W1 = (const float*)d_in[2];
    const float* b1 = (const float*)d_in[3];
    const float* W2 = (const float*)d_in[4];
    const float* b2 = (const float*)d_in[5];
    const float* W3 = (const float*)d_in[6];
    const float* b3 = (const float*)d_in[7];

    // d_ws layout (950,272 B total)
    ushort* W3T = (ushort*)d_ws;                 // 1568*256 fp16 = 802816 B
    ushort* W2T = W3T + 1568 * 256;              // 256*256 fp16
    ushort* W1T = W2T + 256 * 256;               // 256*32 fp16

    float* zout  = (float*)d_out;                // (65536, 32)
    float* ldout = zout + (size_t)65536 * 32;    // (65536,)

    cvt_weights<<<1856, 256, 0, stream>>>(W1, W2, W3, W3T, W2T, W1T);
    rq_mfma<<<1024, 256, 0, stream>>>(x1, x2, b1, b2, b3, W1T, W2T, W3T, zout, ldout);
}

// Round 12
// 235.396 us; speedup vs baseline: 1.1633x; 1.1633x over previous
//
#include <hip/hip_runtime.h>
#include <cmath>

#define NB 16
#define TAILV 3.0f
#define MINV 0.001f
#define CSC 0.984f   // 1 - NB*MINV

typedef __attribute__((ext_vector_type(8))) _Float16 half8;
typedef __attribute__((ext_vector_type(4))) float f32x4;

#define MFMA16(a,b,c) __builtin_amdgcn_mfma_f32_16x16x32_f16(a,b,c,0,0,0)

__device__ __forceinline__ ushort f2h(float f) {
    union { _Float16 h; ushort u; } v; v.h = (_Float16)f; return v.u;
}
__device__ __forceinline__ float softplus_f(float x) {
    return (x > 20.0f) ? x : __logf(1.0f + __expf(x));
}

// ---- prologue: coalesced LDS-tiled transpose into d_ws (fp16, [N][K]) ----
// W3T: [2048][256], n = dim*64 + p (p<49 real, else 0). 128 blocks (32 dims x 4 p-groups).
// W2T: [256][256] via 16 blocks. W1T: [256][32] via 1 block. Grid = 145.
__global__ void __launch_bounds__(256)
cvt_weights(const float* __restrict__ W1, const float* __restrict__ W2,
            const float* __restrict__ W3, const float* __restrict__ b3,
            ushort* __restrict__ W3T, ushort* __restrict__ W2T,
            ushort* __restrict__ W1T, float* __restrict__ b3p)
{
    __shared__ ushort sT[16 * 264];
    const int b = blockIdx.x, t = threadIdx.x;

    if (b < 128) {               // ---- W3T ----
        const int dim = b >> 2, g = b & 3;
        const int n0 = dim * 64 + g * 16;
        // read: 16 k-chunks; lane group = consecutive cols (coalesced)
        const int cl = t & 15, kq = t >> 4;
        const int p  = g * 16 + cl;
        #pragma unroll
        for (int kb = 0; kb < 16; ++kb) {
            int k = kb * 16 + kq;
            float v = (p < 49) ? W3[(size_t)k * 1568 + dim * 49 + p] : 0.0f;
            sT[cl * 264 + k] = f2h(v);
        }
        if (t < 16) b3p[n0 + t] = (g * 16 + t < 49) ? b3[dim * 49 + g * 16 + t] : 0.0f;
        __syncthreads();
        // write: thread t writes 16 contiguous fp16 (32 B), coalesced
        const int r = t >> 4, kc = t & 15;
        #pragma unroll
        for (int j = 0; j < 16; ++j)
            W3T[(size_t)(n0 + r) * 256 + kc * 16 + j] = sT[r * 264 + kc * 16 + j];
    } else if (b < 144) {        // ---- W2T ----
        const int n0 = (b - 128) * 16;
        const int cl = t & 15, kq = t >> 4;
        #pragma unroll
        for (int kb = 0; kb < 16; ++kb) {
            int k = kb * 16 + kq;
            sT[cl * 264 + k] = f2h(W2[(size_t)k * 256 + n0 + cl]);
        }
        __syncthreads();
        const int r = t >> 4, kc = t & 15;
        #pragma unroll
        for (int j = 0; j < 16; ++j)
            W2T[(size_t)(n0 + r) * 256 + kc * 16 + j] = sT[r * 264 + kc * 16 + j];
    } else {                     // ---- W1T (8K elems, 1 block) ----
        #pragma unroll
        for (int k = 0; k < 32; ++k)
            W1T[t * 32 + k] = f2h(W1[k * 256 + t]);   // read coalesced, write 64B/thread
    }
}

// ---- fused main kernel: 64 batch rows / block, 4 waves, 1024 blocks ----
// (round-10 structure: padded W3T, accumulators dead before spline, rot swizzle)
extern "C" __global__ void __launch_bounds__(256, 2)
rq_mfma(const float* __restrict__ x1, const float* __restrict__ x2,
        const float* __restrict__ b1, const float* __restrict__ b2,
        const ushort* __restrict__ W1T, const ushort* __restrict__ W2T,
        const ushort* __restrict__ W3T, const float* __restrict__ b3p,
        float* __restrict__ zout, float* __restrict__ ldout)
{
    __shared__ char smem[60416];
    float*  sX2  = (float*)smem;                    // [64][33] f32 = 8448
    float*  sLDw = (float*)(smem + 8448);           // [64][5] f32 = 1280
    char*   U    = smem + 9728;                     // 50688-byte union
    ushort* R0   = (ushort*)U;                      // [32][264] fp16 = 16896
    ushort* R1   = (ushort*)(U + 16896);            // [32][264]
    ushort* R2   = (ushort*)(U + 33792);            // [32][264]
    ushort* sA1  = R2;                              // [64][40] fp16 = 5120
    float*  sPw  = (float*)U;                       // 4 x [64][49] f32 = 50176

    const int tid  = threadIdx.x;
    const int row0 = blockIdx.x * 64;
    const int rot  = blockIdx.x & 7;
    const int wave = tid >> 6, lane = tid & 63;
    const int ln = lane & 15, kg = lane >> 4;       // frag: m/n=ln, k-group=kg

    // ---- phase 0: stage x1 (->fp16, R2) and x2 (f32) ----
    {
        int r = tid >> 2, c = (tid & 3) << 3;
        float4 v0 = *(const float4*)(x1 + (size_t)(row0 + r) * 32 + c);
        float4 v1 = *(const float4*)(x1 + (size_t)(row0 + r) * 32 + c + 4);
        sA1[r*40 + c    ] = f2h(v0.x); sA1[r*40 + c + 1] = f2h(v0.y);
        sA1[r*40 + c + 2] = f2h(v0.z); sA1[r*40 + c + 3] = f2h(v0.w);
        sA1[r*40 + c + 4] = f2h(v1.x); sA1[r*40 + c + 5] = f2h(v1.y);
        sA1[r*40 + c + 6] = f2h(v1.z); sA1[r*40 + c + 7] = f2h(v1.w);
        float4 w0 = *(const float4*)(x2 + (size_t)(row0 + r) * 32 + c);
        float4 w1 = *(const float4*)(x2 + (size_t)(row0 + r) * 32 + c + 4);
        sX2[r*33 + c    ] = w0.x; sX2[r*33 + c + 1] = w0.y;
        sX2[r*33 + c + 2] = w0.z; sX2[r*33 + c + 3] = w0.w;
        sX2[r*33 + c + 4] = w1.x; sX2[r*33 + c + 5] = w1.y;
        sX2[r*33 + c + 6] = w1.z; sX2[r*33 + c + 7] = w1.w;
    }
    __syncthreads();

    // ---- phase 1: h1 = relu(x1 @ W1 + b1); 4 M-tiles, K=32 ----
    {
        half8 a[4];
        #pragma unroll
        for (int m = 0; m < 4; ++m)
            a[m] = *(const half8*)(sA1 + (m*16 + ln)*40 + kg*8);
        #pragma unroll
        for (int nt = 0; nt < 4; ++nt) {
            int n = wave*64 + nt*16 + ln;
            half8 bfr = *(const half8*)(W1T + n*32 + kg*8);
            float bias = b1[n];
            f32x4 zr = {0.f,0.f,0.f,0.f};
            #pragma unroll
            for (int m = 0; m < 4; ++m) {
                f32x4 cm = MFMA16(a[m], bfr, zr);
                ushort* dst = (m < 2) ? R0 : R1;
                int rb = (m & 1) * 16;
                #pragma unroll
                for (int g = 0; g < 4; ++g)
                    dst[(rb + kg*4 + g)*264 + n] = f2h(fmaxf(cm[g] + bias, 0.f));
            }
        }
    }
    __syncthreads();

    // ---- phase 2: h2 = relu(h1 @ W2 + b2), two 32-row half-passes ----
    #pragma unroll
    for (int part = 0; part < 2; ++part) {
        const ushort* S = (part == 0) ? R0 : R1;   // h1 rows
        ushort*       D = (part == 0) ? R2 : R0;   // h2 rows
        half8 a0[8], a1[8];
        #pragma unroll
        for (int ks = 0; ks < 8; ++ks) {
            a0[ks] = *(const half8*)(S + ln*264 + ks*32 + kg*8);
            a1[ks] = *(const half8*)(S + (16 + ln)*264 + ks*32 + kg*8);
        }
        #pragma unroll
        for (int nt = 0; nt < 4; ++nt) {
            int n = wave*64 + nt*16 + ln;
            f32x4 c0 = {0,0,0,0}, c1 = {0,0,0,0};
            const ushort* bp = W2T + (size_t)n*256 + kg*8;
            #pragma unroll
            for (int ks = 0; ks < 8; ++ks) {
                half8 bfr = *(const half8*)(bp + ks*32);
                c0 = MFMA16(a0[ks], bfr, c0);
                c1 = MFMA16(a1[ks], bfr, c1);
            }
            float bias = b2[n];
            #pragma unroll
            for (int g = 0; g < 4; ++g) {
                D[(kg*4 + g)*264 + n]      = f2h(fmaxf(c0[g] + bias, 0.f));
                D[(16 + kg*4 + g)*264 + n] = f2h(fmaxf(c1[g] + bias, 0.f));
            }
        }
        __syncthreads();
    }

    // ---- phase 3: hoist GEMM3 A-fragments (4 M-tiles x 8 ks = 128 regs) ----
    half8 A[4][8];
    #pragma unroll
    for (int m = 0; m < 4; ++m) {
        const ushort* src = (m < 2) ? R2 : R0;     // h2 rows 0-31 / 32-63
        int rb = (m & 1) * 16;
        #pragma unroll
        for (int ks = 0; ks < 8; ++ks)
            A[m][ks] = *(const half8*)(src + (rb + ln)*264 + ks*32 + kg*8);
    }
    __syncthreads();   // staging dead; sPw overlays U

    // ---- phase 4: GEMM3 + fused spline; wave owns dims [wave*8, wave*8+8) ----
    float* myP = sPw + wave * (64 * 49);
    float  ldacc = 0.f;

    half8 bcur[8], bnxt[8];
    {
        int dim0 = wave*8 + rot;
        const ushort* bp = W3T + (size_t)(dim0*64 + ln)*256 + kg*8;
        #pragma unroll
        for (int ks = 0; ks < 8; ++ks) bcur[ks] = *(const half8*)(bp + ks*32);
    }

    for (int ch0 = 0; ch0 < 8; ++ch0) {
        const int ch  = (ch0 + rot) & 7;
        const int dim = wave*8 + ch;
        const int nb  = dim * 64;
        float bias[4];
        #pragma unroll
        for (int nt = 0; nt < 4; ++nt) bias[nt] = b3p[nb + nt*16 + ln];

        #pragma unroll
        for (int nt = 0; nt < 4; ++nt) {
            const bool last = (ch0 == 7) && (nt == 3);
            if (!last) {   // prefetch next tile (rotated order)
                int ndim = (nt == 3) ? (wave*8 + ((ch0 + 1 + rot) & 7)) : dim;
                int nnt  = (nt == 3) ? 0 : nt + 1;
                const ushort* bp = W3T + (size_t)(ndim*64 + nnt*16 + ln)*256 + kg*8;
                #pragma unroll
                for (int ks = 0; ks < 8; ++ks) bnxt[ks] = *(const half8*)(bp + ks*32);
            }
            f32x4 c[4];
            #pragma unroll
            for (int m = 0; m < 4; ++m) c[m] = (f32x4){0,0,0,0};
            #pragma unroll
            for (int ks = 0; ks < 8; ++ks)
                #pragma unroll
                for (int m = 0; m < 4; ++m)
                    c[m] = MFMA16(A[m][ks], bcur[ks], c[m]);
            int p = nt*16 + ln;
            if (p < 49) {
                #pragma unroll
                for (int m = 0; m < 4; ++m)
                    #pragma unroll
                    for (int g = 0; g < 4; ++g)
                        myP[(m*16 + kg*4 + g)*49 + p] = c[m][g] + bias[nt];
            }
            if (!last) {
                #pragma unroll
                for (int ks = 0; ks < 8; ++ks) bcur[ks] = bnxt[ks];
            }
        }

        // spline: 64 rows x 1 dim = exactly 1 task/lane (r = lane)
        {
            const float* pp = myP + lane * 49;
            const float x  = sX2[lane*33 + dim];
            const float xc = fminf(fmaxf(x, -TAILV), TAILV);

            float e[NB]; float mx = -1e30f;
            #pragma unroll
            for (int k = 0; k < NB; ++k) { e[k] = pp[k]; mx = fmaxf(mx, e[k]); }
            float s = 0.f;
            #pragma unroll
            for (int k = 0; k < NB; ++k) { e[k] = __expf(e[k] - mx); s += e[k]; }
            const float inv = 1.f / s;

            int idx = 0; float xk = -TAILV, xk1 = TAILV, cum = 0.f;
            #pragma unroll
            for (int k = 0; k < NB; ++k) {
                float lo = -TAILV + 2.f * TAILV * cum;
                cum += MINV + CSC * e[k] * inv;
                float hi = -TAILV + 2.f * TAILV * cum;
                if (lo <= xc) { idx = k; xk = lo; xk1 = hi; }
            }

            float eh[NB]; float mh = -1e30f;
            #pragma unroll
            for (int k = 0; k < NB; ++k) { eh[k] = pp[NB + k]; mh = fmaxf(mh, eh[k]); }
            float sh = 0.f;
            #pragma unroll
            for (int k = 0; k < NB; ++k) { eh[k] = __expf(eh[k] - mh); sh += eh[k]; }
            const float invh = 1.f / sh;

            float yk = -TAILV, yk1 = TAILV; cum = 0.f;
            #pragma unroll
            for (int k = 0; k < NB; ++k) {
                float lo = -TAILV + 2.f * TAILV * cum;
                cum += MINV + CSC * eh[k] * invh;
                float hi = -TAILV + 2.f * TAILV * cum;
                if (k == idx) { yk = lo; yk1 = hi; }
            }

            const float d0 = MINV + softplus_f(pp[2*NB + idx]);
            const float d1 = MINV + softplus_f(pp[2*NB + idx + 1]);

            const float wd = xk1 - xk, hd = yk1 - yk;
            const float sk = hd / wd;
            const float xi = (xc - xk) / wd;
            const float xim = xi * (1.f - xi);
            const float alpha = hd * (sk * xi * xi + d0 * xim);
            const float beta  = sk + (d1 + d0 - 2.f * sk) * xim;
            const float z     = yk + alpha / beta;
            const float om    = 1.f - xi;
            const float dn    = sk * sk * (d1 * xi * xi + 2.f * sk * xim + d0 * om * om);
            const float ld    = __logf(dn) - 2.f * __logf(beta);

            const bool inside = (x >= -TAILV) && (x <= TAILV);
            zout[(size_t)(row0 + lane) * 32 + dim] = inside ? z : x;
            ldacc += inside ? ld : 0.f;
        }
    }
    sLDw[lane*5 + wave] = ldacc;
    __syncthreads();

    // ---- phase 5: log_det reduction across waves ----
    if (tid < 64) {
        float sld = sLDw[tid*5 + 0] + sLDw[tid*5 + 1]
                  + sLDw[tid*5 + 2] + sLDw[tid*5 + 3];
        ldout[row0 + tid] = sld;
    }
}

extern "C" void kernel_launch(void* const* d_in, const int* in_sizes, int n_in,
                              void* d_out, int out_size, void* d_ws, size_t ws_size,
                              hipStream_t stream)
{
    const float* x1 = (const float*)d_in[0];
    const float* x2 = (const float*)d_in[1];
    const float* W1 = (const float*)d_in[2];
    const float* b1 = (const float*)d_in[3];
    const float* W2 = (const float*)d_in[4];
    const float* b2 = (const float*)d_in[5];
    const float* W3 = (const float*)d_in[6];
    const float* b3 = (const float*)d_in[7];

    // d_ws layout (1,204,224 B total)
    ushort* W3T = (ushort*)d_ws;                 // 2048*256 fp16 = 1 MB
    ushort* W2T = W3T + 2048 * 256;              // 256*256 fp16
    ushort* W1T = W2T + 256 * 256;               // 256*32 fp16
    float*  b3p = (float*)(W1T + 256 * 32);      // 2048 f32

    float* zout  = (float*)d_out;                // (65536, 32)
    float* ldout = zout + (size_t)65536 * 32;    // (65536,)

    cvt_weights<<<145, 256, 0, stream>>>(W1, W2, W3, b3, W3T, W2T, W1T, b3p);
    rq_mfma<<<1024, 256, 0, stream>>>(x1, x2, b1, b2, W1T, W2T, W3T, b3p, zout, ldout);
}